// Round 7
// baseline (334.983 us; speedup 1.0000x reference)
//
#include <hip/hip_runtime.h>
#include <stdint.h>
#include <stddef.h>

// Problem constants (B=4, L=1024, D=768, H=6, DH=128)
#define BB 4
#define LL 1024
#define DD 768
#define HH 6
#define DHH 128
#define EPS 1e-5f

// Inputs fp32, outputs fp32.
// Output layout (fp32 elements, concatenated in return order):
//   co : (B,H,L,L) = 25165824
//   w  : (B,L,1)   = 4096
//   Vh : (B,H,L,DH)= 3145728
#define CO_ELEMS 25165824
#define W_ELEMS  4096

// ws layout (fp32 elements), ~13 MB. All deterministic writes, no init.
#define OFF_Q2  0           // 24576
#define OFF_K2  24576       // 24576
#define OFF_WC  49152       // 24576  final col sums
#define OFF_SM  73728       // 2*24*2*260 = 24960 (sv[128],tv[128],s2,s22 per which,bh,ks)
#define OFF_AC  98688       // 16
#define OFF_GDP 98704       // 24*8 gram-dot partials
#define OFF_SS  98896       // 96*2 BN2 (sum,sumsq) block partials
#define OFF_GP  99328       // 96*16384 = 1572864 gram partials (which,bh,ks)
#define OFF_WP  1672192     // 64*24*1024 = 1572864 col-sum strip partials
// total 3245056 floats = 12.98 MB

typedef __attribute__((ext_vector_type(8))) short short8;
typedef __attribute__((ext_vector_type(4))) float f32x4;

// load 8 contiguous fp32, truncate to bf16 fragment
__device__ __forceinline__ short8 ld_bf8(const float* __restrict__ p) {
    const float4 a = *(const float4*)(p);
    const float4 b = *(const float4*)(p + 4);
    short8 r;
    r[0] = (short)(__float_as_uint(a.x) >> 16);
    r[1] = (short)(__float_as_uint(a.y) >> 16);
    r[2] = (short)(__float_as_uint(a.z) >> 16);
    r[3] = (short)(__float_as_uint(a.w) >> 16);
    r[4] = (short)(__float_as_uint(b.x) >> 16);
    r[5] = (short)(__float_as_uint(b.y) >> 16);
    r[6] = (short)(__float_as_uint(b.z) >> 16);
    r[7] = (short)(__float_as_uint(b.w) >> 16);
    return r;
}

// ------------------------------------------------- q2 / k2 (row sq-norms)
__global__ void k_rownorm(const float* __restrict__ Q,
                          const float* __restrict__ K,
                          float* __restrict__ ws) {
    int gid = blockIdx.x * 256 + threadIdx.x;       // 196608
    int sub = gid & 3;
    int rg  = gid >> 2;
    int which = (rg >= 24576);
    int rid = which ? rg - 24576 : rg;              // bh*1024 + i
    int bh = rid >> 10, i = rid & 1023;
    int b = bh / HH, h = bh - b * HH;
    const float* src = (which ? K : Q) + (size_t)(b * LL + i) * DD + h * DHH;
    float s = 0.f;
#pragma unroll
    for (int kk = 0; kk < 8; kk++) {
        float4 v = *(const float4*)(src + (sub + 4 * kk) * 4);
        s += v.x * v.x + v.y * v.y + v.z * v.z + v.w * v.w;
    }
    s += __shfl_xor(s, 1);
    s += __shfl_xor(s, 2);
    if (sub == 0) ws[(which ? OFF_K2 : OFF_Q2) + rid] = s;
}

// ------------------------------------------------- Vh output (exact copy)
__global__ void k_vh(const float* __restrict__ V, float* __restrict__ out) {
    int cid = blockIdx.x * 256 + threadIdx.x;       // 786432 float4 chunks
    if (cid >= 786432) return;
    int d4 = cid & 31;
    int rest = cid >> 5;
    int l = rest & 1023;
    int bh = rest >> 10;
    int b = bh / HH, h = bh - b * HH;
    float4 v = *(const float4*)(V + (size_t)(b * LL + l) * DD + h * DHH + d4 * 4);
    *(float4*)(out + (size_t)cid * 4) = v;
}

// ---- Gram partial over K-split + sv/tv/s2/s22 sums (fused, same LDS tile)
// grid (24 bh, 2 which, 2 ks); block 256 = 4 waves (64x64 Gram quadrant each)
__global__ __launch_bounds__(256) void k_gramsum(
        const float* __restrict__ Q, const float* __restrict__ Km,
        const float* __restrict__ ws, float* __restrict__ gramP,
        float* __restrict__ smP) {
    const int bh = blockIdx.x, which = blockIdx.y, ks = blockIdx.z;
    const int b = bh / HH, h = bh - b * HH;
    const float* X  = (which ? Km : Q) + (size_t)b * LL * DD + h * DHH;
    const float* x2 = ws + (which ? OFF_K2 : OFF_Q2) + bh * 1024;
    const int rbase = ks * 512;
    const int tid = threadIdx.x, lane = tid & 63, wave = tid >> 6;
    const int lm = lane & 15, quad = lane >> 4;
    const int m0 = (wave >> 1) * 64, n0 = (wave & 1) * 64;
    __shared__ float xs[32 * 132];
    __shared__ float xs2[32];
    f32x4 acc[4][4];
#pragma unroll
    for (int mi = 0; mi < 4; mi++)
#pragma unroll
        for (int ni = 0; ni < 4; ni++) acc[mi][ni] = (f32x4)(0.0f);
    float sv = 0.f, tv = 0.f, s2p = 0.f, s22p = 0.f;

    for (int kc = 0; kc < 16; kc++) {
        __syncthreads();
#pragma unroll
        for (int s = 0; s < 4; s++) {
            int fidx = s * 256 + tid;
            int row = fidx >> 5, c4 = fidx & 31;
            float4 v = *(const float4*)(X + (size_t)(rbase + kc * 32 + row) * DD + c4 * 4);
            *(float4*)&xs[row * 132 + c4 * 4] = v;
        }
        if (tid < 32) xs2[tid] = x2[rbase + kc * 32 + tid];
        __syncthreads();
        // MFMA quadrant
        short8 am[4], bn[4];
#pragma unroll
        for (int mi = 0; mi < 4; mi++) {
            short8 f;
#pragma unroll
            for (int j = 0; j < 8; j++) {
                float v = xs[(quad * 8 + j) * 132 + m0 + mi * 16 + lm];
                f[j] = (short)(__float_as_uint(v) >> 16);
            }
            am[mi] = f;
        }
#pragma unroll
        for (int ni = 0; ni < 4; ni++) {
            short8 f;
#pragma unroll
            for (int j = 0; j < 8; j++) {
                float v = xs[(quad * 8 + j) * 132 + n0 + ni * 16 + lm];
                f[j] = (short)(__float_as_uint(v) >> 16);
            }
            bn[ni] = f;
        }
#pragma unroll
        for (int mi = 0; mi < 4; mi++)
#pragma unroll
            for (int ni = 0; ni < 4; ni++)
                acc[mi][ni] = __builtin_amdgcn_mfma_f32_16x16x32_bf16(am[mi], bn[ni], acc[mi][ni], 0, 0, 0);
        // fused sums from the same LDS tile
        if (tid < 128) {
#pragma unroll 4
            for (int row = 0; row < 32; row++) {
                float v = xs[row * 132 + tid];
                sv += v; tv += xs2[row] * v;
            }
        }
        if (tid < 32) { float w2 = xs2[tid]; s2p += w2; s22p += w2 * w2; }
    }

    float* G = gramP + (size_t)((which * 24 + bh) * 2 + ks) * 16384;
#pragma unroll
    for (int mi = 0; mi < 4; mi++)
#pragma unroll
        for (int ni = 0; ni < 4; ni++)
#pragma unroll
            for (int r = 0; r < 4; r++)
                G[(m0 + mi * 16 + quad * 4 + r) * 128 + (n0 + ni * 16 + lm)] = acc[mi][ni][r];

    float* sm = smP + (size_t)((which * 24 + bh) * 2 + ks) * 260;
    if (tid < 128) { sm[tid] = sv; sm[128 + tid] = tv; }
    if (tid < 32) {
#pragma unroll
        for (int off = 1; off < 32; off <<= 1) {
            s2p += __shfl_xor(s2p, off);
            s22p += __shfl_xor(s22p, off);
        }
        if (tid == 0) { sm[256] = s2p; sm[257] = s22p; }
    }
}

// ---- Frobenius dot <Gq, Gk> partials: grid (24, 8)
__global__ void k_gdot(const float* __restrict__ gramP, float* __restrict__ gdP) {
    const int bh = blockIdx.x, part = blockIdx.y, t = threadIdx.x;
    const float* q0 = gramP + (size_t)(bh * 2 + 0) * 16384;
    const float* q1 = gramP + (size_t)(bh * 2 + 1) * 16384;
    const float* k0 = gramP + (size_t)((24 + bh) * 2 + 0) * 16384;
    const float* k1 = gramP + (size_t)((24 + bh) * 2 + 1) * 16384;
    float s = 0.f;
#pragma unroll
    for (int it = 0; it < 8; it++) {
        int e = part * 2048 + it * 256 + t;
        s += (q0[e] + q1[e]) * (k0[e] + k1[e]);
    }
#pragma unroll
    for (int off = 1; off < 64; off <<= 1) s += __shfl_xor(s, off);
    __shared__ float sc[4];
    if ((t & 63) == 0) sc[t >> 6] = s;
    __syncthreads();
    if (t == 0) gdP[bh * 8 + part] = sc[0] + sc[1] + sc[2] + sc[3];
}

// ---- closed-form batchnorm stats -> a1, c1 per head
__global__ void k_stats2(const float* __restrict__ smP, const float* __restrict__ gdP,
                         const float* __restrict__ g1, const float* __restrict__ b1,
                         float* __restrict__ ac) {
    const int t = threadIdx.x;
    __shared__ double sA[24], sB[24];
    if (t < 24) {
        const float* q0 = smP + (size_t)(t * 2 + 0) * 260;
        const float* q1 = smP + (size_t)(t * 2 + 1) * 260;
        const float* k0 = smP + (size_t)((24 + t) * 2 + 0) * 260;
        const float* k1 = smP + (size_t)((24 + t) * 2 + 1) * 260;
        double dqk = 0, dtqk = 0, dtkq = 0;
        for (int d = 0; d < 128; d++) {
            double svq = (double)q0[d] + q1[d],       svk = (double)k0[d] + k1[d];
            double tvq = (double)q0[128 + d] + q1[128 + d];
            double tvk = (double)k0[128 + d] + k1[128 + d];
            dqk += svq * svk; dtqk += tvq * svk; dtkq += tvk * svq;
        }
        double s2q = (double)q0[256] + q1[256], s22q = (double)q0[257] + q1[257];
        double s2k = (double)k0[256] + k1[256], s22k = (double)k0[257] + k1[257];
        double gd = 0;
        for (int p = 0; p < 8; p++) gd += gdP[t * 8 + p];
        sA[t] = -1024.0 * (s2q + s2k) + 2.0 * dqk;
        sB[t] = 1024.0 * (s22q + s22k) + 4.0 * gd
              + 2.0 * s2q * s2k - 4.0 * dtqk - 4.0 * dtkq;
    }
    __syncthreads();
    if (t < HH) {
        double hs = 0, hq = 0;
        for (int b = 0; b < 4; b++) { hs += sA[b * HH + t]; hq += sB[b * HH + t]; }
        const double N = 4194304.0;
        double m = hs / N;
        double var = hq / N - m * m;
        if (var < 0) var = 0;
        float r = rsqrtf((float)var + EPS);
        float a = r * g1[t];
        ac[t] = a;
        ac[8 + t] = b1[t] - (float)m * a;
    }
}

// ---- fused: GEMM 16x1024 strip -> BN -> mask -> exp -> row softmax ->
// COALESCED store via LDS transpose (1-KB runs); col-sum strip partials.
__global__ __launch_bounds__(256, 2) void k_fused(
        const float* __restrict__ Q, const float* __restrict__ Km,
        const float* __restrict__ q2, const float* __restrict__ k2,
        const float* __restrict__ ac, const unsigned char* __restrict__ bx,
        float* __restrict__ co, float* __restrict__ wcolP) {
    const int strip = blockIdx.x;         // 64 strips of 16 rows
    const int bh = blockIdx.y;            // 24
    const int b = bh / HH, h = bh - b * HH;
    const int tid = threadIdx.x, lane = tid & 63, wave = tid >> 6;
    const int lm = lane & 15, quad = lane >> 4;
    const int ibase = strip * 16;
    const int colbase = wave * 256;
    const float* Qb = Q + (size_t)b * LL * DD + h * DHH;
    const float* Kb = Km + (size_t)b * LL * DD + h * DHH;

    f32x4 acc[16];
#pragma unroll
    for (int tj = 0; tj < 16; tj++) acc[tj] = (f32x4)(0.0f);

#pragma unroll
    for (int kk = 0; kk < 4; kk++) {
        const int d0 = kk * 32 + quad * 8;
        short8 af = ld_bf8(Qb + (size_t)(ibase + lm) * DD + d0);
#pragma unroll
        for (int tj = 0; tj < 16; tj++) {
            short8 bf = ld_bf8(Kb + (size_t)(colbase + tj * 16 + lm) * DD + d0);
            acc[tj] = __builtin_amdgcn_mfma_f32_16x16x32_bf16(af, bf, acc[tj], 0, 0, 0);
        }
    }

    const float a = ac[h], c = ac[8 + h];
    const unsigned char* bxb = bx + b * LL;
    float q2v[4]; bool vi[4];
#pragma unroll
    for (int r = 0; r < 4; r++) {
        int i = ibase + quad * 4 + r;
        q2v[r] = q2[bh * 1024 + i];
        vi[r] = (bxb[i] == 0);
    }
    float k2v[16]; bool vj[16];
#pragma unroll
    for (int tj = 0; tj < 16; tj++) {
        int j = colbase + tj * 16 + lm;
        k2v[tj] = k2[bh * 1024 + j];
        vj[tj] = (bxb[j] == 0);
    }

    float rp[4] = {0.f, 0.f, 0.f, 0.f};
#pragma unroll
    for (int tj = 0; tj < 16; tj++)
#pragma unroll
        for (int r = 0; r < 4; r++) {
            float S = 2.0f * acc[tj][r] - q2v[r] - k2v[tj];
            float z = (vi[r] && vj[tj]) ? fminf(a * S + c, 60.0f) : 0.0f;
            float e = __expf(z);
            acc[tj][r] = e;
            rp[r] += e;
        }
#pragma unroll
    for (int r = 0; r < 4; r++) {
        rp[r] += __shfl_xor(rp[r], 1);
        rp[r] += __shfl_xor(rp[r], 2);
        rp[r] += __shfl_xor(rp[r], 4);
        rp[r] += __shfl_xor(rp[r], 8);
    }

    __shared__ float rs[16][5];
    __shared__ float invs[16];
    __shared__ float colsum[1024];
    __shared__ float tbuf[4][8 * 264];
    if (lm == 0) {
#pragma unroll
        for (int r = 0; r < 4; r++) rs[quad * 4 + r][wave] = rp[r];
    }
    __syncthreads();
    if (tid < 16) invs[tid] = 1.0f / (rs[tid][0] + rs[tid][1] + rs[tid][2] + rs[tid][3]);
    __syncthreads();
    float iv[4];
#pragma unroll
    for (int r = 0; r < 4; r++) iv[r] = invs[quad * 4 + r];

    float cs[16];
#pragma unroll
    for (int tj = 0; tj < 16; tj++) cs[tj] = 0.f;
#pragma unroll
    for (int tj = 0; tj < 16; tj++)
#pragma unroll
        for (int r = 0; r < 4; r++) {
            float p = acc[tj][r] * iv[r];
            acc[tj][r] = p;
            cs[tj] += p;
        }
    // col sums across quads
#pragma unroll
    for (int tj = 0; tj < 16; tj++) {
        cs[tj] += __shfl_xor(cs[tj], 16);
        cs[tj] += __shfl_xor(cs[tj], 32);
    }
    if (quad == 0) {
#pragma unroll
        for (int tj = 0; tj < 16; tj++) colsum[colbase + tj * 16 + lm] = cs[tj];
    }

    // ---- coalesced store via per-wave LDS transpose (two 8-row rounds)
    float* tbw = &tbuf[wave][0];
    float* cob = co + ((size_t)bh << 20);
    if (quad < 2) {
#pragma unroll
        for (int tj = 0; tj < 16; tj++)
#pragma unroll
            for (int r = 0; r < 4; r++)
                tbw[(quad * 4 + r) * 264 + tj * 16 + lm] = acc[tj][r];
    }
    __syncthreads();
#pragma unroll
    for (int row = 0; row < 8; row++) {
        float4 v = *(const float4*)&tbw[row * 264 + lane * 4];
        *(float4*)&cob[((size_t)(ibase + row) << 10) + colbase + lane * 4] = v;
    }
    __syncthreads();
    if (quad >= 2) {
#pragma unroll
        for (int tj = 0; tj < 16; tj++)
#pragma unroll
            for (int r = 0; r < 4; r++)
                tbw[(quad * 4 + r - 8) * 264 + tj * 16 + lm] = acc[tj][r];
    }
    __syncthreads();
#pragma unroll
    for (int row = 0; row < 8; row++) {
        float4 v = *(const float4*)&tbw[row * 264 + lane * 4];
        *(float4*)&cob[((size_t)(ibase + 8 + row) << 10) + colbase + lane * 4] = v;
    }
    __syncthreads();
    float4 wv = *(const float4*)&colsum[tid * 4];
    *(float4*)&wcolP[((size_t)strip * 24 + bh) * 1024 + tid * 4] = wv;
}

// ---- reduce col-sum strip partials -> wcol; fused BN2 block partials
__global__ void k_wcol_reduce(const float* __restrict__ wcolP,
                              float* __restrict__ wcol, float* __restrict__ ws2) {
    const int t = threadIdx.x;
    int g = blockIdx.x * 256 + t;                    // 24576
    float s = 0.f;
#pragma unroll 8
    for (int strip = 0; strip < 64; strip++)
        s += wcolP[(size_t)strip * 24576 + g];
    wcol[g] = s;
    float sq = s * s;
    float a = s, b = sq;
#pragma unroll
    for (int off = 1; off < 64; off <<= 1) { a += __shfl_xor(a, off); b += __shfl_xor(b, off); }
    __shared__ float sc[4][2];
    if ((t & 63) == 0) { sc[t >> 6][0] = a; sc[t >> 6][1] = b; }
    __syncthreads();
    if (t == 0) {
        ws2[blockIdx.x * 2]     = sc[0][0] + sc[1][0] + sc[2][0] + sc[3][0];
        ws2[blockIdx.x * 2 + 1] = sc[0][1] + sc[1][1] + sc[2][1] + sc[3][1];
    }
}

// ------- tail: BN2 (from block partials) + gate + per-batch softmax
__global__ __launch_bounds__(1024) void k_tail(
        const float* __restrict__ wcol, const float* __restrict__ ws2,
        const unsigned char* __restrict__ bx,
        const float* __restrict__ g2, const float* __restrict__ b2,
        const float* __restrict__ Wp, const float* __restrict__ bp,
        float* __restrict__ wout) {
    const int t = threadIdx.x, lane = t & 63, wv = t >> 6;
    __shared__ float abuf[12];       // a2s[0..5], c2s[6..11]
    __shared__ float xb[4096];
    __shared__ float wred[16][2];

    if (t < HH) {
        float s = 0.f, s2 = 0.f;
        for (int b = 0; b < 4; b++) {
            int bh = b * HH + t;
#pragma unroll
            for (int sub = 0; sub < 4; sub++) {
                int blk = bh * 4 + sub;
                s += ws2[blk * 2];
                s2 += ws2[blk * 2 + 1];
            }
        }
        float m = s / 4096.f;
        float var = fmaxf(s2 / 4096.f - m * m, 0.0f);
        float r = rsqrtf(var + EPS);
        float a = r * g2[t];
        abuf[t] = a;
        abuf[6 + t] = b2[t] - m * a;
    }
    __syncthreads();

    const float bp0 = bp[0], bp1 = bp[1];
#pragma unroll
    for (int p = 0; p < 4; p++) {
        int idx = t + p * 1024;
        int b = idx >> 10, l = idx & 1023;
        float z0 = bp0, z1 = bp1;
#pragma unroll
        for (int h = 0; h < HH; h++) {
            float wn = abuf[h] * wcol[(size_t)(b * HH + h) * 1024 + l] + abuf[6 + h];
            z0 += wn * Wp[h];
            z1 += wn * Wp[HH + h];
        }
        float pc = 1.0f / (1.0f + __expf(z1 - z0));
        xb[idx] = bx[b * LL + l] ? -INFINITY : pc;
    }
    __syncthreads();

    const int bb = t >> 8, tb = t & 255;
    float4 xv = *(const float4*)&xb[bb * 1024 + tb * 4];
    float mx = fmaxf(fmaxf(xv.x, xv.y), fmaxf(xv.z, xv.w));
#pragma unroll
    for (int off = 1; off < 64; off <<= 1) mx = fmaxf(mx, __shfl_xor(mx, off));
    if (lane == 0) wred[wv][0] = mx;
    __syncthreads();
    mx = fmaxf(fmaxf(wred[bb * 4][0], wred[bb * 4 + 1][0]),
               fmaxf(wred[bb * 4 + 2][0], wred[bb * 4 + 3][0]));
    float e0 = __expf(xv.x - mx), e1 = __expf(xv.y - mx);
    float e2 = __expf(xv.z - mx), e3 = __expf(xv.w - mx);
    float ss = e0 + e1 + e2 + e3;
#pragma unroll
    for (int off = 1; off < 64; off <<= 1) ss += __shfl_xor(ss, off);
    if (lane == 0) wred[wv][1] = ss;
    __syncthreads();
    float sum = wred[bb * 4][1] + wred[bb * 4 + 1][1] + wred[bb * 4 + 2][1] + wred[bb * 4 + 3][1];
    float4 o;
    o.x = e0 / sum; o.y = e1 / sum; o.z = e2 / sum; o.w = e3 / sum;
    *(float4*)&wout[bb * 1024 + tb * 4] = o;
}

extern "C" void kernel_launch(void* const* d_in, const int* in_sizes, int n_in,
                              void* d_out, int out_size, void* d_ws, size_t ws_size,
                              hipStream_t stream) {
    const float* Q  = (const float*)d_in[0];
    const float* K  = (const float*)d_in[1];
    const float* V  = (const float*)d_in[2];
    // d_in[3] = pad_mask — derivable from bx_packed, unused
    const unsigned char* bx = (const unsigned char*)d_in[4];
    const float* g1 = (const float*)d_in[5];
    const float* b1 = (const float*)d_in[6];
    const float* g2 = (const float*)d_in[7];
    const float* b2 = (const float*)d_in[8];
    const float* Wp = (const float*)d_in[9];
    const float* bp = (const float*)d_in[10];

    float* out  = (float*)d_out;
    float* co   = out;                        // (B,H,L,L)
    float* wout = out + CO_ELEMS;             // (B,L,1)
    float* vh   = out + CO_ELEMS + W_ELEMS;   // (B,H,L,DH)

    float* ws = (float*)d_ws;                 // ~13 MB
    float* q2    = ws + OFF_Q2;
    float* k2    = ws + OFF_K2;
    float* wcol  = ws + OFF_WC;
    float* smP   = ws + OFF_SM;
    float* ac    = ws + OFF_AC;
    float* gdP   = ws + OFF_GDP;
    float* ws2   = ws + OFF_SS;
    float* gramP = ws + OFF_GP;
    float* wcolP = ws + OFF_WP;

    k_rownorm<<<768, 256, 0, stream>>>(Q, K, ws);
    k_gramsum<<<dim3(24, 2, 2), 256, 0, stream>>>(Q, K, ws, gramP, smP);
    k_vh<<<3072, 256, 0, stream>>>(V, vh);
    k_gdot<<<dim3(24, 8), 256, 0, stream>>>(gramP, gdP);
    k_stats2<<<1, 256, 0, stream>>>(smP, gdP, g1, b1, ac);
    k_fused<<<dim3(64, 24), 256, 0, stream>>>(Q, K, q2, k2, ac, bx, co, wcolP);
    k_wcol_reduce<<<96, 256, 0, stream>>>(wcolP, wcol, ws2);
    k_tail<<<1, 1024, 0, stream>>>(wcol, ws2, bx, g2, b2, Wp, bp, wout);
}

// Round 9
// 274.615 us; speedup vs baseline: 1.2198x; 1.2198x over previous
//
#include <hip/hip_runtime.h>
#include <stdint.h>
#include <stddef.h>

// Problem constants (B=4, L=1024, D=768, H=6, DH=128)
#define BB 4
#define LL 1024
#define DD 768
#define HH 6
#define DHH 128
#define EPS 1e-5f

// Inputs fp32, outputs fp32.
// Output layout (fp32 elements, concatenated in return order):
//   co : (B,H,L,L) = 25165824
//   w  : (B,L,1)   = 4096
//   Vh : (B,H,L,DH)= 3145728
#define CO_ELEMS 25165824
#define W_ELEMS  4096

// ws layout (fp32 elements), ~6.6 MB. All deterministic writes, no atomics.
#define OFF_Q2  0           // 24576
#define OFF_K2  24576       // 24576
#define OFF_WC  49152       // 24576  final col sums
#define OFF_SP  73728       // 6144   per-block (sum,sumsq) BN1 partials
#define OFF_AC  79872       // 16     a1[0..7], c1[8..15]
#define OFF_SS  79888       // 192    BN2 (sum,sumsq) block partials
#define OFF_WP  81920       // 64*24*1024 = 1572864 col-sum strip partials
// total 1654784 floats = 6.62 MB

typedef __attribute__((ext_vector_type(8))) short short8;
typedef __attribute__((ext_vector_type(4))) float f32x4;

// load 8 contiguous fp32, truncate to bf16 fragment
__device__ __forceinline__ short8 ld_bf8(const float* __restrict__ p) {
    const float4 a = *(const float4*)(p);
    const float4 b = *(const float4*)(p + 4);
    short8 r;
    r[0] = (short)(__float_as_uint(a.x) >> 16);
    r[1] = (short)(__float_as_uint(a.y) >> 16);
    r[2] = (short)(__float_as_uint(a.z) >> 16);
    r[3] = (short)(__float_as_uint(a.w) >> 16);
    r[4] = (short)(__float_as_uint(b.x) >> 16);
    r[5] = (short)(__float_as_uint(b.y) >> 16);
    r[6] = (short)(__float_as_uint(b.z) >> 16);
    r[7] = (short)(__float_as_uint(b.w) >> 16);
    return r;
}

// ------------------------------------------------- q2 / k2 (row sq-norms)
__global__ void k_rownorm(const float* __restrict__ Q,
                          const float* __restrict__ K,
                          float* __restrict__ ws) {
    int gid = blockIdx.x * 256 + threadIdx.x;       // 196608
    int sub = gid & 3;
    int rg  = gid >> 2;
    int which = (rg >= 24576);
    int rid = which ? rg - 24576 : rg;              // bh*1024 + i
    int bh = rid >> 10, i = rid & 1023;
    int b = bh / HH, h = bh - b * HH;
    const float* src = (which ? K : Q) + (size_t)(b * LL + i) * DD + h * DHH;
    float s = 0.f;
#pragma unroll
    for (int kk = 0; kk < 8; kk++) {
        float4 v = *(const float4*)(src + (sub + 4 * kk) * 4);
        s += v.x * v.x + v.y * v.y + v.z * v.z + v.w * v.w;
    }
    s += __shfl_xor(s, 1);
    s += __shfl_xor(s, 2);
    if (sub == 0) ws[(which ? OFF_K2 : OFF_Q2) + rid] = s;
}

// ------------------------------------------------- Vh output (exact copy)
__global__ void k_vh(const float* __restrict__ V, float* __restrict__ out) {
    int cid = blockIdx.x * 256 + threadIdx.x;       // 786432 float4 chunks
    if (cid >= 786432) return;
    int d4 = cid & 31;
    int rest = cid >> 5;
    int l = rest & 1023;
    int bh = rest >> 10;
    int b = bh / HH, h = bh - b * HH;
    f32x4 v = *(const f32x4*)(V + (size_t)(b * LL + l) * DD + h * DHH + d4 * 4);
    __builtin_nontemporal_store(v, (f32x4*)(out + (size_t)cid * 4));
}

// ---- pass 1: write RAW S (fp32) to co AND accumulate BN1 block partials
// (proven 78-us structure from R5; scatter dword stores, no LDS transpose)
__global__ __launch_bounds__(256) void k_gemm_S(
        const float* __restrict__ Q, const float* __restrict__ Km,
        const float* __restrict__ q2, const float* __restrict__ k2,
        float* __restrict__ co, float* __restrict__ statsP) {
    const int bh = blockIdx.z, b = bh / HH, h = bh - b * HH;
    const int tid = threadIdx.x, lane = tid & 63, wave = tid >> 6;
    const int wr = wave >> 1, wc = wave & 1;
    const int ibase = blockIdx.y * 64 + wr * 32;
    const int jbase = blockIdx.x * 128 + wc * 64;
    const int lm = lane & 15, quad = lane >> 4;
    const float* Qb = Q + (size_t)b * LL * DD + h * DHH;
    const float* Kb = Km + (size_t)b * LL * DD + h * DHH;

    f32x4 acc[2][4];
#pragma unroll
    for (int ti = 0; ti < 2; ti++)
#pragma unroll
        for (int tj = 0; tj < 4; tj++) acc[ti][tj] = (f32x4)(0.0f);

#pragma unroll
    for (int kk = 0; kk < 4; kk++) {
        const int d0 = kk * 32 + quad * 8;
        short8 af[2], bfr[4];
        af[0] = ld_bf8(Qb + (size_t)(ibase + lm) * DD + d0);
        af[1] = ld_bf8(Qb + (size_t)(ibase + 16 + lm) * DD + d0);
#pragma unroll
        for (int tj = 0; tj < 4; tj++)
            bfr[tj] = ld_bf8(Kb + (size_t)(jbase + tj * 16 + lm) * DD + d0);
#pragma unroll
        for (int ti = 0; ti < 2; ti++)
#pragma unroll
            for (int tj = 0; tj < 4; tj++)
                acc[ti][tj] = __builtin_amdgcn_mfma_f32_16x16x32_bf16(af[ti], bfr[tj], acc[ti][tj], 0, 0, 0);
    }

    float q2v[2][4], k2v[4];
#pragma unroll
    for (int ti = 0; ti < 2; ti++)
#pragma unroll
        for (int r = 0; r < 4; r++)
            q2v[ti][r] = q2[bh * 1024 + ibase + ti * 16 + quad * 4 + r];
#pragma unroll
    for (int tj = 0; tj < 4; tj++)
        k2v[tj] = k2[bh * 1024 + jbase + tj * 16 + lm];

    float s = 0.f, s2 = 0.f;
#pragma unroll
    for (int ti = 0; ti < 2; ti++)
#pragma unroll
        for (int tj = 0; tj < 4; tj++)
#pragma unroll
            for (int r = 0; r < 4; r++) {
                int i = ibase + ti * 16 + quad * 4 + r;
                int j = jbase + tj * 16 + lm;
                float S = 2.0f * acc[ti][tj][r] - q2v[ti][r] - k2v[tj];
                co[(size_t)(bh * 1024 + i) * 1024 + j] = S;
                s += S; s2 += S * S;
            }

    __shared__ float rA[256], rB[256];
    rA[tid] = s; rB[tid] = s2;
    __syncthreads();
    for (int off = 128; off > 0; off >>= 1) {
        if (tid < off) { rA[tid] += rA[tid + off]; rB[tid] += rB[tid + off]; }
        __syncthreads();
    }
    if (tid == 0) {
        int blk = blockIdx.y * 8 + blockIdx.x;         // 0..127
        int base = (bh * 128 + blk) * 2;
        statsP[base] = rA[0];
        statsP[base + 1] = rB[0];
    }
}

// --------------------------------------------- reduce BN1 stats -> ac
__global__ void k_stats(const float* __restrict__ statsP,
                        const float* __restrict__ g1, const float* __restrict__ b1,
                        float* __restrict__ ac) {
    __shared__ float rA[256], rB[256];
    const int t = threadIdx.x;
    for (int h = 0; h < HH; h++) {
        float s = 0.f, s2 = 0.f;
        for (int m = t; m < 512; m += 256) {           // 4 batches * 128 blocks
            int b = m >> 7, blk = m & 127;
            int base = ((b * HH + h) * 128 + blk) * 2;
            s += statsP[base]; s2 += statsP[base + 1];
        }
        rA[t] = s; rB[t] = s2;
        __syncthreads();
        for (int off = 128; off > 0; off >>= 1) {
            if (t < off) { rA[t] += rA[t + off]; rB[t] += rB[t + off]; }
            __syncthreads();
        }
        if (t == 0) {
            const float N = 4194304.f;                 // 4*1024*1024
            float m_ = rA[0] / N;
            float var = fmaxf(rB[0] / N - m_ * m_, 0.0f);
            float r = rsqrtf(var + EPS);
            float a = r * g1[h];
            ac[h] = a;
            ac[8 + h] = b1[h] - m_ * a;
        }
        __syncthreads();
    }
}

// ---- pass 2: read S (mostly LLC-resident), e = exp(masked BN(S)),
// row softmax in-block (16 full rows, coalesced float4), nontemporal write p,
// deterministic col-sum strip partials (NO global atomics).
__global__ __launch_bounds__(256) void k_normexp(
        float* __restrict__ co, const float* __restrict__ ac,
        const unsigned char* __restrict__ bx, float* __restrict__ wcolP) {
    const int bh = blockIdx.y;            // 24
    const int b = bh / HH, h = bh - b * HH;
    const int strip = blockIdx.x;         // 64 strips of 16 rows
    const int t = threadIdx.x;            // col group: cols 4t..4t+3
    float* base = co + ((size_t)bh << 20) + ((size_t)strip << 14);
    const float a = ac[h], c = ac[8 + h];

    const unsigned char* bxb = bx + b * LL;
    const uchar4 m4 = *(const uchar4*)(bxb + t * 4);
    const bool vj0 = (m4.x == 0), vj1 = (m4.y == 0), vj2 = (m4.z == 0), vj3 = (m4.w == 0);

    f32x4 buf[16];
    float rp[16];
#pragma unroll
    for (int r = 0; r < 16; r++) {
        const int i = strip * 16 + r;
        const bool vi = (bxb[i] == 0);
        f32x4 s4 = *(const f32x4*)(base + r * 1024 + t * 4);
        f32x4 e;
        e[0] = (vi && vj0) ? __expf(fminf(a * s4[0] + c, 60.0f)) : 1.0f;
        e[1] = (vi && vj1) ? __expf(fminf(a * s4[1] + c, 60.0f)) : 1.0f;
        e[2] = (vi && vj2) ? __expf(fminf(a * s4[2] + c, 60.0f)) : 1.0f;
        e[3] = (vi && vj3) ? __expf(fminf(a * s4[3] + c, 60.0f)) : 1.0f;
        buf[r] = e;
        rp[r] = e[0] + e[1] + e[2] + e[3];
    }

    __shared__ float pr[16][257];
    __shared__ float pr2[16][17];
    __shared__ float inv[16];
#pragma unroll
    for (int r = 0; r < 16; r++) pr[r][t] = rp[r];
    __syncthreads();
    {
        int r = t >> 4, k = t & 15;
        float s = 0.f;
#pragma unroll
        for (int j = 0; j < 16; j++) s += pr[r][k * 16 + j];
        pr2[r][k] = s;
    }
    __syncthreads();
    if (t < 16) {
        float s = 0.f;
#pragma unroll
        for (int k = 0; k < 16; k++) s += pr2[t][k];
        inv[t] = 1.0f / s;
    }
    __syncthreads();

    float cs0 = 0.f, cs1 = 0.f, cs2 = 0.f, cs3 = 0.f;
#pragma unroll
    for (int r = 0; r < 16; r++) {
        const float iv = inv[r];
        f32x4 v = buf[r];
        v[0] *= iv; v[1] *= iv; v[2] *= iv; v[3] *= iv;
        __builtin_nontemporal_store(v, (f32x4*)(base + r * 1024 + t * 4));
        cs0 += v[0]; cs1 += v[1]; cs2 += v[2]; cs3 += v[3];
    }
    float4 wv; wv.x = cs0; wv.y = cs1; wv.z = cs2; wv.w = cs3;
    *(float4*)&wcolP[((size_t)strip * 24 + bh) * 1024 + t * 4] = wv;
}

// ---- reduce col-sum strip partials -> wcol; fused BN2 block partials
__global__ void k_wcol_reduce(const float* __restrict__ wcolP,
                              float* __restrict__ wcol, float* __restrict__ ws2) {
    const int t = threadIdx.x;
    int g = blockIdx.x * 256 + t;                    // 24576
    float s = 0.f;
#pragma unroll 8
    for (int strip = 0; strip < 64; strip++)
        s += wcolP[(size_t)strip * 24576 + g];
    wcol[g] = s;
    float a = s, b = s * s;
#pragma unroll
    for (int off = 1; off < 64; off <<= 1) { a += __shfl_xor(a, off); b += __shfl_xor(b, off); }
    __shared__ float sc[4][2];
    if ((t & 63) == 0) { sc[t >> 6][0] = a; sc[t >> 6][1] = b; }
    __syncthreads();
    if (t == 0) {
        ws2[blockIdx.x * 2]     = sc[0][0] + sc[1][0] + sc[2][0] + sc[3][0];
        ws2[blockIdx.x * 2 + 1] = sc[0][1] + sc[1][1] + sc[2][1] + sc[3][1];
    }
}

// ------- tail: BN2 (from block partials) + gate + per-batch softmax
__global__ __launch_bounds__(1024) void k_tail(
        const float* __restrict__ wcol, const float* __restrict__ ws2,
        const unsigned char* __restrict__ bx,
        const float* __restrict__ g2, const float* __restrict__ b2,
        const float* __restrict__ Wp, const float* __restrict__ bp,
        float* __restrict__ wout) {
    const int t = threadIdx.x, lane = t & 63, wv = t >> 6;
    __shared__ float abuf[12];       // a2s[0..5], c2s[6..11]
    __shared__ float xb[4096];
    __shared__ float wred[16][2];

    if (t < HH) {
        float s = 0.f, s2 = 0.f;
        for (int b = 0; b < 4; b++) {
            int bh = b * HH + t;
#pragma unroll
            for (int sub = 0; sub < 4; sub++) {
                int blk = bh * 4 + sub;
                s += ws2[blk * 2];
                s2 += ws2[blk * 2 + 1];
            }
        }
        float m = s / 4096.f;
        float var = fmaxf(s2 / 4096.f - m * m, 0.0f);
        float r = rsqrtf(var + EPS);
        float a = r * g2[t];
        abuf[t] = a;
        abuf[6 + t] = b2[t] - m * a;
    }
    __syncthreads();

    const float bp0 = bp[0], bp1 = bp[1];
#pragma unroll
    for (int p = 0; p < 4; p++) {
        int idx = t + p * 1024;
        int b = idx >> 10, l = idx & 1023;
        float z0 = bp0, z1 = bp1;
#pragma unroll
        for (int h = 0; h < HH; h++) {
            float wn = abuf[h] * wcol[(size_t)(b * HH + h) * 1024 + l] + abuf[6 + h];
            z0 += wn * Wp[h];
            z1 += wn * Wp[HH + h];
        }
        float pc = 1.0f / (1.0f + __expf(z1 - z0));
        xb[idx] = bx[b * LL + l] ? -INFINITY : pc;
    }
    __syncthreads();

    const int bb = t >> 8, tb = t & 255;
    float4 xv = *(const float4*)&xb[bb * 1024 + tb * 4];
    float mx = fmaxf(fmaxf(xv.x, xv.y), fmaxf(xv.z, xv.w));
#pragma unroll
    for (int off = 1; off < 64; off <<= 1) mx = fmaxf(mx, __shfl_xor(mx, off));
    if (lane == 0) wred[wv][0] = mx;
    __syncthreads();
    mx = fmaxf(fmaxf(wred[bb * 4][0], wred[bb * 4 + 1][0]),
               fmaxf(wred[bb * 4 + 2][0], wred[bb * 4 + 3][0]));
    float e0 = __expf(xv.x - mx), e1 = __expf(xv.y - mx);
    float e2 = __expf(xv.z - mx), e3 = __expf(xv.w - mx);
    float ss = e0 + e1 + e2 + e3;
#pragma unroll
    for (int off = 1; off < 64; off <<= 1) ss += __shfl_xor(ss, off);
    if (lane == 0) wred[wv][1] = ss;
    __syncthreads();
    float sum = wred[bb * 4][1] + wred[bb * 4 + 1][1] + wred[bb * 4 + 2][1] + wred[bb * 4 + 3][1];
    float4 o;
    o.x = e0 / sum; o.y = e1 / sum; o.z = e2 / sum; o.w = e3 / sum;
    *(float4*)&wout[bb * 1024 + tb * 4] = o;
}

extern "C" void kernel_launch(void* const* d_in, const int* in_sizes, int n_in,
                              void* d_out, int out_size, void* d_ws, size_t ws_size,
                              hipStream_t stream) {
    const float* Q  = (const float*)d_in[0];
    const float* K  = (const float*)d_in[1];
    const float* V  = (const float*)d_in[2];
    // d_in[3] = pad_mask — derivable from bx_packed, unused
    const unsigned char* bx = (const unsigned char*)d_in[4];
    const float* g1 = (const float*)d_in[5];
    const float* b1 = (const float*)d_in[6];
    const float* g2 = (const float*)d_in[7];
    const float* b2 = (const float*)d_in[8];
    const float* Wp = (const float*)d_in[9];
    const float* bp = (const float*)d_in[10];

    float* out  = (float*)d_out;
    float* co   = out;                        // (B,H,L,L)
    float* wout = out + CO_ELEMS;             // (B,L,1)
    float* vh   = out + CO_ELEMS + W_ELEMS;   // (B,H,L,DH)

    float* ws = (float*)d_ws;                 // ~6.6 MB
    float* q2     = ws + OFF_Q2;
    float* k2     = ws + OFF_K2;
    float* wcol   = ws + OFF_WC;
    float* statsP = ws + OFF_SP;
    float* ac     = ws + OFF_AC;
    float* ws2    = ws + OFF_SS;
    float* wcolP  = ws + OFF_WP;

    k_rownorm<<<768, 256, 0, stream>>>(Q, K, ws);
    k_vh<<<3072, 256, 0, stream>>>(V, vh);
    k_gemm_S<<<dim3(8, 16, BB * HH), 256, 0, stream>>>(Q, K, q2, k2, co, statsP);
    k_stats<<<1, 256, 0, stream>>>(statsP, g1, b1, ac);
    k_normexp<<<dim3(64, 24), 256, 0, stream>>>(co, ac, bx, wcolP);
    k_wcol_reduce<<<96, 256, 0, stream>>>(wcolP, wcol, ws2);
    k_tail<<<1, 1024, 0, stream>>>(wcol, ws2, bx, g2, b2, Wp, bp, wout);
}